// Round 2
// baseline (180.802 us; speedup 1.0000x reference)
//
#include <hip/hip_runtime.h>

#define NB 512
#define SLOTS 32
#define D 1024
#define D4 256           // D/4 (float4 per row)
#define TC 16            // tokens per chunk
#define MAX_TOK 512
#define TAU_INV 10.0f
#define NW 16            // waves per block
#define BT 1024          // threads per block

__global__ __launch_bounds__(BT, 4)
void cam_read_kernel(const float* __restrict__ query,    // [NT][D]
                     const int*   __restrict__ tids,     // [NT]
                     const float* __restrict__ skeys,    // [NB*SLOTS][D]
                     const float* __restrict__ svals,    // [NB*SLOTS][D]
                     const int*   __restrict__ stids,    // [NB*SLOTS]
                     const float* __restrict__ centroid, // [NB][D]
                     float*       __restrict__ out,      // [NT][D]
                     int n_tokens)
{
    const int bucket = blockIdx.x;
    const int tidx   = threadIdx.x;      // 0..1023
    const int lane   = tidx & 63;
    const int wid    = tidx >> 6;        // 0..15

    __shared__ float s_anchor[D];
    __shared__ float s_uq[TC][D];
    __shared__ float s_scores[TC][SLOTS];
    __shared__ float s_probs[TC][SLOTS];
    __shared__ int   s_toklist[MAX_TOK];
    __shared__ int   s_toktid[TC];
    __shared__ int   s_wcnt[NW];

    // ---- anchor row (first 256 threads, one float4 each) ----
    if (tidx < D4)
        ((float4*)s_anchor)[tidx] = ((const float4*)centroid)[bucket * D4 + tidx];

    // ---- parallel scan: wave w scans its own segment ----
    const int seg     = ((n_tokens + NW * 64 - 1) / (NW * 64)) * 64;
    const int sbegin  = wid * seg;
    const int send    = min(sbegin + seg, n_tokens);
    int wcnt = 0;
    for (int base = sbegin; base < send; base += 64) {
        int idx = base + lane;
        bool m = (idx < send) && ((tids[idx] & (NB - 1)) == bucket);
        wcnt += __popcll(__ballot(m));
    }
    if (lane == 0) s_wcnt[wid] = wcnt;
    __syncthreads();

    int offs = 0, total = 0;
    #pragma unroll
    for (int i = 0; i < NW; ++i) {
        int c = s_wcnt[i];
        if (i < wid) offs += c;
        total += c;
    }
    // second pass: write compacted indices at this wave's offset
    {
        int pos = offs;
        for (int base = sbegin; base < send; base += 64) {
            int idx = base + lane;
            bool m = (idx < send) && ((tids[idx] & (NB - 1)) == bucket);
            unsigned long long mask = __ballot(m);
            if (m) {
                int p = pos + __popcll(mask & ((1ull << lane) - 1ull));
                if (p < MAX_TOK) s_toklist[p] = idx;
            }
            pos += __popcll(mask);
        }
    }
    __syncthreads();

    const int count = min(total, MAX_TOK);
    if (count == 0) return;

    for (int c0 = 0; c0 < count; c0 += TC) {
        const int nt = min(TC, count - c0);

        // ---- unified queries: wave w owns token w (all 16 concurrent) ----
        if (wid < nt) {
            const int tok = s_toklist[c0 + wid];
            const float4* q4 = (const float4*)(query + (size_t)tok * D);
            float4 qv[4];
            float ss = 0.f;
            #pragma unroll
            for (int j = 0; j < 4; ++j) {
                qv[j] = q4[lane + 64 * j];
                ss += qv[j].x*qv[j].x + qv[j].y*qv[j].y + qv[j].z*qv[j].z + qv[j].w*qv[j].w;
            }
            #pragma unroll
            for (int off = 32; off >= 1; off >>= 1) ss += __shfl_xor(ss, off);
            const float qn = 0.5f / fmaxf(sqrtf(ss), 1e-12f);   // folds ALPHA=0.5

            float4 uv[4];
            float ss2 = 0.f;
            #pragma unroll
            for (int j = 0; j < 4; ++j) {
                float4 av = ((const float4*)s_anchor)[lane + 64 * j];
                uv[j].x = qv[j].x * qn + 0.5f * av.x;
                uv[j].y = qv[j].y * qn + 0.5f * av.y;
                uv[j].z = qv[j].z * qn + 0.5f * av.z;
                uv[j].w = qv[j].w * qn + 0.5f * av.w;
                ss2 += uv[j].x*uv[j].x + uv[j].y*uv[j].y + uv[j].z*uv[j].z + uv[j].w*uv[j].w;
            }
            #pragma unroll
            for (int off = 32; off >= 1; off >>= 1) ss2 += __shfl_xor(ss2, off);
            const float un = 1.0f / fmaxf(sqrtf(ss2), 1e-12f);
            #pragma unroll
            for (int j = 0; j < 4; ++j) {
                float4 w4 = make_float4(uv[j].x*un, uv[j].y*un, uv[j].z*un, uv[j].w*un);
                ((float4*)s_uq[wid])[lane + 64 * j] = w4;
            }
            if (lane == 0) s_toktid[wid] = tids[tok];
        }
        __syncthreads();

        // ---- scores: wave w owns slots 2w and 2w+1 (all 32 concurrent) ----
        {
            const int s0 = wid * 2;
            const float4* k0 = (const float4*)(skeys + ((size_t)bucket * SLOTS + s0) * D);
            const float4* k1 = k0 + D4;
            float4 ka[4], kb[4];
            #pragma unroll
            for (int j = 0; j < 4; ++j) { ka[j] = k0[lane + 64 * j]; kb[j] = k1[lane + 64 * j]; }
            for (int t = 0; t < nt; ++t) {
                const float4* u4 = (const float4*)s_uq[t];
                float a = 0.f, b = 0.f;
                #pragma unroll
                for (int j = 0; j < 4; ++j) {
                    float4 u = u4[lane + 64 * j];
                    a += ka[j].x*u.x + ka[j].y*u.y + ka[j].z*u.z + ka[j].w*u.w;
                    b += kb[j].x*u.x + kb[j].y*u.y + kb[j].z*u.z + kb[j].w*u.w;
                }
                #pragma unroll
                for (int off = 32; off >= 1; off >>= 1) {
                    a += __shfl_xor(a, off);
                    b += __shfl_xor(b, off);
                }
                if (lane == 0) { s_scores[t][s0] = a; s_scores[t][s0 + 1] = b; }
            }
        }
        __syncthreads();

        // ---- softmax + hard-match: wave t owns token t, lanes 0..31 ----
        if (wid < nt && lane < 32) {
            const int t = wid;
            const int s = lane;
            const float sc = s_scores[t][s];
            const int match = (stids[bucket * SLOTS + s] == s_toktid[t]) ? 1 : 0;
            float mx = sc;
            #pragma unroll
            for (int off = 16; off >= 1; off >>= 1) mx = fmaxf(mx, __shfl_xor(mx, off));
            const float e = expf((sc - mx) * TAU_INV);
            float es = e;
            int   ms = match;
            #pragma unroll
            for (int off = 16; off >= 1; off >>= 1) {
                es += __shfl_xor(es, off);
                ms += __shfl_xor(ms, off);
            }
            float p;
            if (ms > 0) p = (float)match / ((float)ms + 1e-9f);
            else        p = e / es;
            s_probs[t][s] = p;
        }
        __syncthreads();

        // ---- values: thread = (grp 0..3, float4 col 0..255); ×4 unrolled prefetch ----
        {
            const int col = tidx & 255;
            const int grp = tidx >> 8;
            float4 acc[4];
            #pragma unroll
            for (int k = 0; k < 4; ++k) acc[k] = make_float4(0.f, 0.f, 0.f, 0.f);

            const float4* vbase = (const float4*)(svals + (size_t)bucket * SLOTS * D);
            for (int s0 = 0; s0 < SLOTS; s0 += 4) {
                float4 v0 = vbase[(s0 + 0) * D4 + col];
                float4 v1 = vbase[(s0 + 1) * D4 + col];
                float4 v2 = vbase[(s0 + 2) * D4 + col];
                float4 v3 = vbase[(s0 + 3) * D4 + col];
                #pragma unroll
                for (int k = 0; k < 4; ++k) {
                    const int t = grp + 4 * k;
                    if (t < nt) {
                        const float p0 = s_probs[t][s0];
                        const float p1 = s_probs[t][s0 + 1];
                        const float p2 = s_probs[t][s0 + 2];
                        const float p3 = s_probs[t][s0 + 3];
                        acc[k].x += p0*v0.x + p1*v1.x + p2*v2.x + p3*v3.x;
                        acc[k].y += p0*v0.y + p1*v1.y + p2*v2.y + p3*v3.y;
                        acc[k].z += p0*v0.z + p1*v1.z + p2*v2.z + p3*v3.z;
                        acc[k].w += p0*v0.w + p1*v1.w + p2*v2.w + p3*v3.w;
                    }
                }
            }
            #pragma unroll
            for (int k = 0; k < 4; ++k) {
                const int t = grp + 4 * k;
                if (t < nt) {
                    const int tok = s_toklist[c0 + t];
                    ((float4*)(out + (size_t)tok * D))[col] = acc[k];
                }
            }
        }
        __syncthreads();   // LDS reused next chunk
    }
}

extern "C" void kernel_launch(void* const* d_in, const int* in_sizes, int n_in,
                              void* d_out, int out_size, void* d_ws, size_t ws_size,
                              hipStream_t stream) {
    const float* query    = (const float*)d_in[0];
    const int*   tids     = (const int*)  d_in[1];
    const float* skeys    = (const float*)d_in[2];
    const float* svals    = (const float*)d_in[3];
    const int*   stids    = (const int*)  d_in[4];
    const float* centroid = (const float*)d_in[5];
    float* out = (float*)d_out;
    const int n_tokens = in_sizes[1];

    cam_read_kernel<<<NB, BT, 0, stream>>>(query, tids, skeys, svals, stids,
                                           centroid, out, n_tokens);
}

// Round 3
// 153.684 us; speedup vs baseline: 1.1765x; 1.1765x over previous
//
#include <hip/hip_runtime.h>

#define NB 512
#define SLOTS 32
#define D 1024
#define D4 256           // D/4 (float4 per row)
#define TC 8             // tokens per chunk (per half-block)
#define CAP 64           // list capacity per bucket
#define TAU_INV 10.0f

// ---- kernel 0: zero the per-bucket counters ----
__global__ void k_zero(int* __restrict__ cnt) {
    if (threadIdx.x < NB) cnt[threadIdx.x] = 0;
}

// ---- kernel 1: build per-bucket token lists (order nondeterministic;
//      output is order-invariant: each token's FP ops are fixed) ----
__global__ void k_build(const int* __restrict__ tids, int n,
                        int* __restrict__ cnt, int* __restrict__ list) {
    int i = blockIdx.x * 256 + threadIdx.x;
    if (i < n) {
        int b = tids[i] & (NB - 1);
        int p = atomicAdd(&cnt[b], 1);
        if (p < CAP) list[b * CAP + p] = i;
    }
}

// ---- kernel 2: main. block = (bucket, half); processes tokens at list
//      positions half, half+2, ... so two blocks share one bucket. ----
__global__ __launch_bounds__(256, 4)
void k_main(const float* __restrict__ query,    // [NT][D]
            const int*   __restrict__ tids,     // [NT]
            const float* __restrict__ skeys,    // [NB*SLOTS][D]
            const float* __restrict__ svals,    // [NB*SLOTS][D]
            const int*   __restrict__ stids,    // [NB*SLOTS]
            const float* __restrict__ centroid, // [NB][D]
            float*       __restrict__ out,      // [NT][D]
            const int*   __restrict__ cnt,
            const int*   __restrict__ list)
{
    const int bucket = blockIdx.x >> 1;
    const int half   = blockIdx.x & 1;
    const int tidx   = threadIdx.x;      // 0..255
    const int lane   = tidx & 63;
    const int wid    = tidx >> 6;        // 0..3

    const int count = min(cnt[bucket], CAP);
    const int ncnt  = (count - half + 1) >> 1;   // tokens owned by this half
    if (ncnt <= 0) return;

    __shared__ float s_anchor[D];
    __shared__ float s_uq[TC][D];
    __shared__ float s_scores[TC][SLOTS];
    __shared__ float s_probs[TC][SLOTS];
    __shared__ int   s_tok[TC];
    __shared__ int   s_ttid[TC];

    if (tidx < D4)
        ((float4*)s_anchor)[tidx] = ((const float4*)centroid)[bucket * D4 + tidx];
    __syncthreads();

    for (int c0 = 0; c0 < ncnt; c0 += TC) {
        const int nt = min(TC, ncnt - c0);

        // ---- unified queries: wave w handles own-tokens t = w, w+4 ----
        for (int t = wid; t < nt; t += 4) {
            const int tok = list[bucket * CAP + half + 2 * (c0 + t)];
            const float4* q4 = (const float4*)(query + (size_t)tok * D);
            float4 qv[4];
            float ss = 0.f;
            #pragma unroll
            for (int j = 0; j < 4; ++j) {
                qv[j] = q4[lane + 64 * j];
                ss += qv[j].x*qv[j].x + qv[j].y*qv[j].y + qv[j].z*qv[j].z + qv[j].w*qv[j].w;
            }
            #pragma unroll
            for (int off = 32; off >= 1; off >>= 1) ss += __shfl_xor(ss, off);
            const float qn = 0.5f / fmaxf(sqrtf(ss), 1e-12f);   // folds ALPHA=0.5

            float4 uv[4];
            float ss2 = 0.f;
            #pragma unroll
            for (int j = 0; j < 4; ++j) {
                float4 av = ((const float4*)s_anchor)[lane + 64 * j];
                uv[j].x = qv[j].x * qn + 0.5f * av.x;
                uv[j].y = qv[j].y * qn + 0.5f * av.y;
                uv[j].z = qv[j].z * qn + 0.5f * av.z;
                uv[j].w = qv[j].w * qn + 0.5f * av.w;
                ss2 += uv[j].x*uv[j].x + uv[j].y*uv[j].y + uv[j].z*uv[j].z + uv[j].w*uv[j].w;
            }
            #pragma unroll
            for (int off = 32; off >= 1; off >>= 1) ss2 += __shfl_xor(ss2, off);
            const float un = 1.0f / fmaxf(sqrtf(ss2), 1e-12f);
            #pragma unroll
            for (int j = 0; j < 4; ++j) {
                float4 w4 = make_float4(uv[j].x*un, uv[j].y*un, uv[j].z*un, uv[j].w*un);
                ((float4*)s_uq[t])[lane + 64 * j] = w4;
            }
            if (lane == 0) { s_tok[t] = tok; s_ttid[t] = tids[tok]; }
        }
        __syncthreads();

        // ---- scores: wave w owns slots [8w, 8w+8), 2 at a time ----
        {
            const float4* krow = (const float4*)(skeys + ((size_t)bucket * SLOTS + wid * 8) * D);
            for (int sp = 0; sp < 8; sp += 2) {
                const float4* k0 = krow + sp * D4;
                const float4* k1 = k0 + D4;
                float4 ka[4], kb[4];
                #pragma unroll
                for (int j = 0; j < 4; ++j) { ka[j] = k0[lane + 64*j]; kb[j] = k1[lane + 64*j]; }
                for (int t = 0; t < nt; ++t) {
                    const float4* u4 = (const float4*)s_uq[t];
                    float a = 0.f, b = 0.f;
                    #pragma unroll
                    for (int j = 0; j < 4; ++j) {
                        float4 u = u4[lane + 64*j];
                        a += ka[j].x*u.x + ka[j].y*u.y + ka[j].z*u.z + ka[j].w*u.w;
                        b += kb[j].x*u.x + kb[j].y*u.y + kb[j].z*u.z + kb[j].w*u.w;
                    }
                    #pragma unroll
                    for (int off = 32; off >= 1; off >>= 1) {
                        a += __shfl_xor(a, off);
                        b += __shfl_xor(b, off);
                    }
                    if (lane == 0) {
                        s_scores[t][wid*8 + sp]     = a;
                        s_scores[t][wid*8 + sp + 1] = b;
                    }
                }
            }
        }
        __syncthreads();

        // ---- softmax + hard-match: wave w handles tokens w, w+4 ----
        for (int t = wid; t < nt; t += 4) {
            if (lane < 32) {
                const int s = lane;
                const float sc = s_scores[t][s];
                const int match = (stids[bucket * SLOTS + s] == s_ttid[t]) ? 1 : 0;
                float mx = sc;
                #pragma unroll
                for (int off = 16; off >= 1; off >>= 1) mx = fmaxf(mx, __shfl_xor(mx, off));
                const float e = expf((sc - mx) * TAU_INV);
                float es = e;
                int   ms = match;
                #pragma unroll
                for (int off = 16; off >= 1; off >>= 1) {
                    es += __shfl_xor(es, off);
                    ms += __shfl_xor(ms, off);
                }
                float p;
                if (ms > 0) p = (float)match / ((float)ms + 1e-9f);
                else        p = e / es;
                s_probs[t][s] = p;
            }
        }
        __syncthreads();

        // ---- values: thread owns float4 column tidx; ×4 slot prefetch ----
        {
            float4 acc[TC];
            #pragma unroll
            for (int t = 0; t < TC; ++t) acc[t] = make_float4(0.f, 0.f, 0.f, 0.f);

            const float4* vb = (const float4*)(svals + (size_t)bucket * SLOTS * D);
            for (int s0 = 0; s0 < SLOTS; s0 += 4) {
                float4 v0 = vb[(s0 + 0) * D4 + tidx];
                float4 v1 = vb[(s0 + 1) * D4 + tidx];
                float4 v2 = vb[(s0 + 2) * D4 + tidx];
                float4 v3 = vb[(s0 + 3) * D4 + tidx];
                #pragma unroll
                for (int t = 0; t < TC; ++t) {
                    if (t < nt) {
                        const float p0 = s_probs[t][s0];
                        const float p1 = s_probs[t][s0 + 1];
                        const float p2 = s_probs[t][s0 + 2];
                        const float p3 = s_probs[t][s0 + 3];
                        acc[t].x += p0*v0.x + p1*v1.x + p2*v2.x + p3*v3.x;
                        acc[t].y += p0*v0.y + p1*v1.y + p2*v2.y + p3*v3.y;
                        acc[t].z += p0*v0.z + p1*v1.z + p2*v2.z + p3*v3.z;
                        acc[t].w += p0*v0.w + p1*v1.w + p2*v2.w + p3*v3.w;
                    }
                }
            }
            #pragma unroll
            for (int t = 0; t < TC; ++t) {
                if (t < nt) {
                    ((float4*)(out + (size_t)s_tok[t] * D))[tidx] = acc[t];
                }
            }
        }
        __syncthreads();   // LDS reused next chunk
    }
}

extern "C" void kernel_launch(void* const* d_in, const int* in_sizes, int n_in,
                              void* d_out, int out_size, void* d_ws, size_t ws_size,
                              hipStream_t stream) {
    const float* query    = (const float*)d_in[0];
    const int*   tids     = (const int*)  d_in[1];
    const float* skeys    = (const float*)d_in[2];
    const float* svals    = (const float*)d_in[3];
    const int*   stids    = (const int*)  d_in[4];
    const float* centroid = (const float*)d_in[5];
    float* out = (float*)d_out;
    const int n_tokens = in_sizes[1];

    int* cnt  = (int*)d_ws;             // [NB]
    int* list = cnt + NB;               // [NB*CAP]

    k_zero<<<1, NB, 0, stream>>>(cnt);
    k_build<<<(n_tokens + 255) / 256, 256, 0, stream>>>(tids, n_tokens, cnt, list);
    k_main<<<NB * 2, 256, 0, stream>>>(query, tids, skeys, svals, stids,
                                       centroid, out, cnt, list);
}

// Round 4
// 87.355 us; speedup vs baseline: 2.0697x; 1.7593x over previous
//
#include <hip/hip_runtime.h>

#define NB 512
#define SLOTS 32
#define D 1024
#define D4 256           // D/4 (float4 per row)
#define TC 8             // tokens per chunk (per half-block)
#define CAP 64           // list capacity per bucket
#define TAU_INV 10.0f

// ---- kernel 0: zero the per-bucket counters ----
__global__ void k_zero(int* __restrict__ cnt) {
    if (threadIdx.x < NB) cnt[threadIdx.x] = 0;
}

// ---- kernel 1: build per-bucket token lists (order nondeterministic;
//      output is order-invariant: each token's FP ops are fixed) ----
__global__ void k_build(const int* __restrict__ tids, int n,
                        int* __restrict__ cnt, int* __restrict__ list) {
    int i = blockIdx.x * 256 + threadIdx.x;
    if (i < n) {
        int b = tids[i] & (NB - 1);
        int p = atomicAdd(&cnt[b], 1);
        if (p < CAP) list[b * CAP + p] = i;
    }
}

// ---- kernel 2: main. block = (bucket, half); two blocks share one bucket.
//      __launch_bounds__(256,2): cap 256 VGPRs — (.,4) made the allocator
//      target 64 VGPRs and spill ~160MB of scratch (R2/R3 post-mortems).
__global__ __launch_bounds__(256, 2)
void k_main(const float* __restrict__ query,    // [NT][D]
            const int*   __restrict__ tids,     // [NT]
            const float* __restrict__ skeys,    // [NB*SLOTS][D]
            const float* __restrict__ svals,    // [NB*SLOTS][D]
            const int*   __restrict__ stids,    // [NB*SLOTS]
            const float* __restrict__ centroid, // [NB][D]
            float*       __restrict__ out,      // [NT][D]
            const int*   __restrict__ cnt,
            const int*   __restrict__ list)
{
    const int bucket = blockIdx.x >> 1;
    const int half   = blockIdx.x & 1;
    const int tidx   = threadIdx.x;      // 0..255
    const int lane   = tidx & 63;
    const int wid    = tidx >> 6;        // 0..3

    const int count = min(cnt[bucket], CAP);
    const int ncnt  = (count - half + 1) >> 1;   // tokens owned by this half
    if (ncnt <= 0) return;

    __shared__ float s_anchor[D];
    __shared__ float s_uq[TC][D];
    __shared__ float s_scores[TC][SLOTS];
    __shared__ float s_probs[TC][SLOTS];
    __shared__ int   s_tok[TC];
    __shared__ int   s_ttid[TC];

    if (tidx < D4)
        ((float4*)s_anchor)[tidx] = ((const float4*)centroid)[bucket * D4 + tidx];
    __syncthreads();

    for (int c0 = 0; c0 < ncnt; c0 += TC) {
        const int nt = min(TC, ncnt - c0);

        // ---- unified queries: wave w handles own-tokens t = w, w+4 ----
        for (int t = wid; t < nt; t += 4) {
            const int tok = list[bucket * CAP + half + 2 * (c0 + t)];
            const float4* q4 = (const float4*)(query + (size_t)tok * D);
            float4 qv[4];
            float ss = 0.f;
            #pragma unroll
            for (int j = 0; j < 4; ++j) {
                qv[j] = q4[lane + 64 * j];
                ss += qv[j].x*qv[j].x + qv[j].y*qv[j].y + qv[j].z*qv[j].z + qv[j].w*qv[j].w;
            }
            #pragma unroll
            for (int off = 32; off >= 1; off >>= 1) ss += __shfl_xor(ss, off);
            const float qn = 0.5f / fmaxf(sqrtf(ss), 1e-12f);   // folds ALPHA=0.5

            float4 uv[4];
            float ss2 = 0.f;
            #pragma unroll
            for (int j = 0; j < 4; ++j) {
                float4 av = ((const float4*)s_anchor)[lane + 64 * j];
                uv[j].x = qv[j].x * qn + 0.5f * av.x;
                uv[j].y = qv[j].y * qn + 0.5f * av.y;
                uv[j].z = qv[j].z * qn + 0.5f * av.z;
                uv[j].w = qv[j].w * qn + 0.5f * av.w;
                ss2 += uv[j].x*uv[j].x + uv[j].y*uv[j].y + uv[j].z*uv[j].z + uv[j].w*uv[j].w;
            }
            #pragma unroll
            for (int off = 32; off >= 1; off >>= 1) ss2 += __shfl_xor(ss2, off);
            const float un = 1.0f / fmaxf(sqrtf(ss2), 1e-12f);
            #pragma unroll
            for (int j = 0; j < 4; ++j) {
                float4 w4 = make_float4(uv[j].x*un, uv[j].y*un, uv[j].z*un, uv[j].w*un);
                ((float4*)s_uq[t])[lane + 64 * j] = w4;
            }
            if (lane == 0) { s_tok[t] = tok; s_ttid[t] = tids[tok]; }
        }
        __syncthreads();

        // ---- scores: wave w owns slots [8w, 8w+8), 2 at a time ----
        {
            const float4* krow = (const float4*)(skeys + ((size_t)bucket * SLOTS + wid * 8) * D);
            for (int sp = 0; sp < 8; sp += 2) {
                const float4* k0 = krow + sp * D4;
                const float4* k1 = k0 + D4;
                float4 ka[4], kb[4];
                #pragma unroll
                for (int j = 0; j < 4; ++j) { ka[j] = k0[lane + 64*j]; kb[j] = k1[lane + 64*j]; }
                for (int t = 0; t < nt; ++t) {
                    const float4* u4 = (const float4*)s_uq[t];
                    float a = 0.f, b = 0.f;
                    #pragma unroll
                    for (int j = 0; j < 4; ++j) {
                        float4 u = u4[lane + 64*j];
                        a += ka[j].x*u.x + ka[j].y*u.y + ka[j].z*u.z + ka[j].w*u.w;
                        b += kb[j].x*u.x + kb[j].y*u.y + kb[j].z*u.z + kb[j].w*u.w;
                    }
                    #pragma unroll
                    for (int off = 32; off >= 1; off >>= 1) {
                        a += __shfl_xor(a, off);
                        b += __shfl_xor(b, off);
                    }
                    if (lane == 0) {
                        s_scores[t][wid*8 + sp]     = a;
                        s_scores[t][wid*8 + sp + 1] = b;
                    }
                }
            }
        }
        __syncthreads();

        // ---- softmax + hard-match: wave w handles tokens w, w+4 ----
        for (int t = wid; t < nt; t += 4) {
            if (lane < 32) {
                const int s = lane;
                const float sc = s_scores[t][s];
                const int match = (stids[bucket * SLOTS + s] == s_ttid[t]) ? 1 : 0;
                float mx = sc;
                #pragma unroll
                for (int off = 16; off >= 1; off >>= 1) mx = fmaxf(mx, __shfl_xor(mx, off));
                const float e = expf((sc - mx) * TAU_INV);
                float es = e;
                int   ms = match;
                #pragma unroll
                for (int off = 16; off >= 1; off >>= 1) {
                    es += __shfl_xor(es, off);
                    ms += __shfl_xor(ms, off);
                }
                float p;
                if (ms > 0) p = (float)match / ((float)ms + 1e-9f);
                else        p = e / es;
                s_probs[t][s] = p;
            }
        }
        __syncthreads();

        // ---- values: thread owns float4 column tidx; ×4 slot prefetch ----
        {
            float4 acc[TC];
            #pragma unroll
            for (int t = 0; t < TC; ++t) acc[t] = make_float4(0.f, 0.f, 0.f, 0.f);

            const float4* vb = (const float4*)(svals + (size_t)bucket * SLOTS * D);
            for (int s0 = 0; s0 < SLOTS; s0 += 4) {
                float4 v0 = vb[(s0 + 0) * D4 + tidx];
                float4 v1 = vb[(s0 + 1) * D4 + tidx];
                float4 v2 = vb[(s0 + 2) * D4 + tidx];
                float4 v3 = vb[(s0 + 3) * D4 + tidx];
                #pragma unroll
                for (int t = 0; t < TC; ++t) {
                    if (t < nt) {
                        const float p0 = s_probs[t][s0];
                        const float p1 = s_probs[t][s0 + 1];
                        const float p2 = s_probs[t][s0 + 2];
                        const float p3 = s_probs[t][s0 + 3];
                        acc[t].x += p0*v0.x + p1*v1.x + p2*v2.x + p3*v3.x;
                        acc[t].y += p0*v0.y + p1*v1.y + p2*v2.y + p3*v3.y;
                        acc[t].z += p0*v0.z + p1*v1.z + p2*v2.z + p3*v3.z;
                        acc[t].w += p0*v0.w + p1*v1.w + p2*v2.w + p3*v3.w;
                    }
                }
            }
            #pragma unroll
            for (int t = 0; t < TC; ++t) {
                if (t < nt) {
                    ((float4*)(out + (size_t)s_tok[t] * D))[tidx] = acc[t];
                }
            }
        }
        __syncthreads();   // LDS reused next chunk
    }
}

extern "C" void kernel_launch(void* const* d_in, const int* in_sizes, int n_in,
                              void* d_out, int out_size, void* d_ws, size_t ws_size,
                              hipStream_t stream) {
    const float* query    = (const float*)d_in[0];
    const int*   tids     = (const int*)  d_in[1];
    const float* skeys    = (const float*)d_in[2];
    const float* svals    = (const float*)d_in[3];
    const int*   stids    = (const int*)  d_in[4];
    const float* centroid = (const float*)d_in[5];
    float* out = (float*)d_out;
    const int n_tokens = in_sizes[1];

    int* cnt  = (int*)d_ws;             // [NB]
    int* list = cnt + NB;               // [NB*CAP]

    k_zero<<<1, NB, 0, stream>>>(cnt);
    k_build<<<(n_tokens + 255) / 256, 256, 0, stream>>>(tids, n_tokens, cnt, list);
    k_main<<<NB * 2, 256, 0, stream>>>(query, tids, skeys, svals, stids,
                                       centroid, out, cnt, list);
}

// Round 5
// 68.027 us; speedup vs baseline: 2.6578x; 1.2841x over previous
//
#include <hip/hip_runtime.h>

#define NB 512
#define SLOTS 32
#define D 1024
#define D4 256           // D/4 (float4 per row)
#define TC 16            // tokens per chunk
#define CAP 64           // list capacity per bucket
#define TAU_INV 10.0f
#define BT 512           // threads per block (8 waves)

// ---- kernel 0: zero the per-bucket counters ----
__global__ void k_zero(int* __restrict__ cnt) {
    if (threadIdx.x < NB) cnt[threadIdx.x] = 0;
}

// ---- kernel 1: build per-bucket token lists (order nondeterministic, but
//      per-token math is order-invariant → deterministic output) ----
__global__ void k_build(const int* __restrict__ tids, int n,
                        int* __restrict__ cnt, int* __restrict__ list) {
    int i = blockIdx.x * 256 + threadIdx.x;
    if (i < n) {
        int b = tids[i] & (NB - 1);
        int p = atomicAdd(&cnt[b], 1);
        if (p < CAP) list[b * CAP + p] = i;
    }
}

// ---- kernel 2: one block per bucket, 8 waves.
//      launch_bounds(512,2): VGPR cap 256 — (.,4) caused 64-reg spills (R2/R3).
__global__ __launch_bounds__(BT, 2)
void k_main(const float* __restrict__ query,    // [NT][D]
            const int*   __restrict__ tids,     // [NT]
            const float* __restrict__ skeys,    // [NB*SLOTS][D]
            const float* __restrict__ svals,    // [NB*SLOTS][D]
            const int*   __restrict__ stids,    // [NB*SLOTS]
            const float* __restrict__ centroid, // [NB][D]
            float*       __restrict__ out,      // [NT][D]
            const int*   __restrict__ cnt,
            const int*   __restrict__ list)
{
    const int bucket = blockIdx.x;
    const int tidx   = threadIdx.x;      // 0..511
    const int lane   = tidx & 63;
    const int wid    = tidx >> 6;        // 0..7

    const int count = min(cnt[bucket], CAP);
    if (count == 0) return;

    __shared__ float s_anchor[D];
    __shared__ float s_uq[TC][D];        // reused as partial-sum buffer in value phase
    __shared__ float s_scores[TC][SLOTS];
    __shared__ float s_probs[TC][SLOTS];
    __shared__ int   s_tok[TC];
    __shared__ int   s_ttid[TC];

    if (tidx < D4)
        ((float4*)s_anchor)[tidx] = ((const float4*)centroid)[bucket * D4 + tidx];
    __syncthreads();

    for (int c0 = 0; c0 < count; c0 += TC) {
        const int nt = min(TC, count - c0);

        // ---- unified queries: wave w owns tokens w, w+8 ----
        for (int t = wid; t < nt; t += 8) {
            const int tok = list[bucket * CAP + c0 + t];
            const float4* q4 = (const float4*)(query + (size_t)tok * D);
            float4 qv[4];
            float ss = 0.f;
            #pragma unroll
            for (int j = 0; j < 4; ++j) {
                qv[j] = q4[lane + 64 * j];
                ss += qv[j].x*qv[j].x + qv[j].y*qv[j].y + qv[j].z*qv[j].z + qv[j].w*qv[j].w;
            }
            #pragma unroll
            for (int off = 32; off >= 1; off >>= 1) ss += __shfl_xor(ss, off);
            const float qn = 0.5f / fmaxf(sqrtf(ss), 1e-12f);   // folds ALPHA=0.5

            float4 uv[4];
            float ss2 = 0.f;
            #pragma unroll
            for (int j = 0; j < 4; ++j) {
                float4 av = ((const float4*)s_anchor)[lane + 64 * j];
                uv[j].x = qv[j].x * qn + 0.5f * av.x;
                uv[j].y = qv[j].y * qn + 0.5f * av.y;
                uv[j].z = qv[j].z * qn + 0.5f * av.z;
                uv[j].w = qv[j].w * qn + 0.5f * av.w;
                ss2 += uv[j].x*uv[j].x + uv[j].y*uv[j].y + uv[j].z*uv[j].z + uv[j].w*uv[j].w;
            }
            #pragma unroll
            for (int off = 32; off >= 1; off >>= 1) ss2 += __shfl_xor(ss2, off);
            const float un = 1.0f / fmaxf(sqrtf(ss2), 1e-12f);
            #pragma unroll
            for (int j = 0; j < 4; ++j) {
                float4 w4 = make_float4(uv[j].x*un, uv[j].y*un, uv[j].z*un, uv[j].w*un);
                ((float4*)s_uq[t])[lane + 64 * j] = w4;
            }
            if (lane == 0) { s_tok[t] = tok; s_ttid[t] = tids[tok]; }
        }
        __syncthreads();

        // ---- scores: wave w owns slots [4w, 4w+4); all 16 key-f4 loads in flight ----
        {
            const float4* kr = (const float4*)(skeys + ((size_t)bucket * SLOTS + wid * 4) * D);
            float4 k0[4], k1[4], k2[4], k3[4];
            #pragma unroll
            for (int j = 0; j < 4; ++j) {
                k0[j] = kr[0 * D4 + lane + 64 * j];
                k1[j] = kr[1 * D4 + lane + 64 * j];
                k2[j] = kr[2 * D4 + lane + 64 * j];
                k3[j] = kr[3 * D4 + lane + 64 * j];
            }
            for (int t = 0; t < nt; ++t) {
                const float4* u4 = (const float4*)s_uq[t];
                float a0 = 0.f, a1 = 0.f, a2 = 0.f, a3 = 0.f;
                #pragma unroll
                for (int j = 0; j < 4; ++j) {
                    float4 u = u4[lane + 64 * j];
                    a0 += k0[j].x*u.x + k0[j].y*u.y + k0[j].z*u.z + k0[j].w*u.w;
                    a1 += k1[j].x*u.x + k1[j].y*u.y + k1[j].z*u.z + k1[j].w*u.w;
                    a2 += k2[j].x*u.x + k2[j].y*u.y + k2[j].z*u.z + k2[j].w*u.w;
                    a3 += k3[j].x*u.x + k3[j].y*u.y + k3[j].z*u.z + k3[j].w*u.w;
                }
                #pragma unroll
                for (int off = 32; off >= 1; off >>= 1) {
                    a0 += __shfl_xor(a0, off);
                    a1 += __shfl_xor(a1, off);
                    a2 += __shfl_xor(a2, off);
                    a3 += __shfl_xor(a3, off);
                }
                if (lane == 0) {
                    s_scores[t][wid*4 + 0] = a0;
                    s_scores[t][wid*4 + 1] = a1;
                    s_scores[t][wid*4 + 2] = a2;
                    s_scores[t][wid*4 + 3] = a3;
                }
            }
        }
        __syncthreads();

        // ---- softmax + hard-match: wave w owns tokens w, w+8; lanes 0..31 ----
        for (int t = wid; t < nt; t += 8) {
            if (lane < 32) {
                const int s = lane;
                const float sc = s_scores[t][s];
                const int match = (stids[bucket * SLOTS + s] == s_ttid[t]) ? 1 : 0;
                float mx = sc;
                #pragma unroll
                for (int off = 16; off >= 1; off >>= 1) mx = fmaxf(mx, __shfl_xor(mx, off));
                const float e = expf((sc - mx) * TAU_INV);
                float es = e;
                int   ms = match;
                #pragma unroll
                for (int off = 16; off >= 1; off >>= 1) {
                    es += __shfl_xor(es, off);
                    ms += __shfl_xor(ms, off);
                }
                float p;
                if (ms > 0) p = (float)match / ((float)ms + 1e-9f);
                else        p = e / es;
                s_probs[t][s] = p;
            }
        }
        __syncthreads();

        // ---- values: grp = tidx>>8 (0/1) covers slots [16g,16g+16); col = tidx&255.
        //      Each grp: 2 rounds of 8 row-loads in flight, partial acc for all 16 tokens.
        {
            const int col = tidx & 255;
            const int grp = tidx >> 8;
            float4 acc[TC];
            #pragma unroll
            for (int t = 0; t < TC; ++t) acc[t] = make_float4(0.f, 0.f, 0.f, 0.f);

            const float4* vb = (const float4*)(svals + ((size_t)bucket * SLOTS + grp * 16) * D);
            #pragma unroll
            for (int s0 = 0; s0 < 16; s0 += 8) {
                float4 v[8];
                #pragma unroll
                for (int i = 0; i < 8; ++i) v[i] = vb[(s0 + i) * D4 + col];
                #pragma unroll
                for (int t = 0; t < TC; ++t) {
                    if (t < nt) {
                        const float4 pA = ((const float4*)s_probs[t])[grp*4 + (s0>>3)*2 + 0];
                        const float4 pB = ((const float4*)s_probs[t])[grp*4 + (s0>>3)*2 + 1];
                        acc[t].x += pA.x*v[0].x + pA.y*v[1].x + pA.z*v[2].x + pA.w*v[3].x
                                  + pB.x*v[4].x + pB.y*v[5].x + pB.z*v[6].x + pB.w*v[7].x;
                        acc[t].y += pA.x*v[0].y + pA.y*v[1].y + pA.z*v[2].y + pA.w*v[3].y
                                  + pB.x*v[4].y + pB.y*v[5].y + pB.z*v[6].y + pB.w*v[7].y;
                        acc[t].z += pA.x*v[0].z + pA.y*v[1].z + pA.z*v[2].z + pA.w*v[3].z
                                  + pB.x*v[4].z + pB.y*v[5].z + pB.z*v[6].z + pB.w*v[7].z;
                        acc[t].w += pA.x*v[0].w + pA.y*v[1].w + pA.z*v[2].w + pA.w*v[3].w
                                  + pB.x*v[4].w + pB.y*v[5].w + pB.z*v[6].w + pB.w*v[7].w;
                    }
                }
            }
            // combine the two slot-half partials through LDS (reuse s_uq)
            if (grp == 0) {
                #pragma unroll
                for (int t = 0; t < TC; ++t)
                    if (t < nt) ((float4*)s_uq[t])[col] = acc[t];
            }
            __syncthreads();
            if (grp == 1) {
                #pragma unroll
                for (int t = 0; t < TC; ++t) {
                    if (t < nt) {
                        float4 b = ((float4*)s_uq[t])[col];
                        float4 r = make_float4(acc[t].x + b.x, acc[t].y + b.y,
                                               acc[t].z + b.z, acc[t].w + b.w);
                        ((float4*)(out + (size_t)s_tok[t] * D))[col] = r;
                    }
                }
            }
        }
        __syncthreads();   // LDS reused next chunk
    }
}

extern "C" void kernel_launch(void* const* d_in, const int* in_sizes, int n_in,
                              void* d_out, int out_size, void* d_ws, size_t ws_size,
                              hipStream_t stream) {
    const float* query    = (const float*)d_in[0];
    const int*   tids     = (const int*)  d_in[1];
    const float* skeys    = (const float*)d_in[2];
    const float* svals    = (const float*)d_in[3];
    const int*   stids    = (const int*)  d_in[4];
    const float* centroid = (const float*)d_in[5];
    float* out = (float*)d_out;
    const int n_tokens = in_sizes[1];

    int* cnt  = (int*)d_ws;             // [NB]
    int* list = cnt + NB;               // [NB*CAP]

    k_zero<<<1, NB, 0, stream>>>(cnt);
    k_build<<<(n_tokens + 255) / 256, 256, 0, stream>>>(tids, n_tokens, cnt, list);
    k_main<<<NB, BT, 0, stream>>>(query, tids, skeys, svals, stids,
                                  centroid, out, cnt, list);
}